// Round 6
// baseline (96.388 us; speedup 1.0000x reference)
//
#include <hip/hip_runtime.h>

typedef float f32x4  __attribute__((ext_vector_type(4)));
typedef short bf16x8 __attribute__((ext_vector_type(8)));
typedef unsigned short u16;

#define BATCH 4
#define NPTS  8192
#define CTW   8                 // col tiles per wave -> 128 cols
#define CG    (NPTS/(16*CTW))   // 64 col groups per batch
#define RCH   16                // row chunks per batch (512 rows each)
#define RTW   32                // row tiles per chunk
#define WPD   (BATCH*CG*RCH)    // 4096 waves per direction

// RNE bf16 split: x ~= h + l
__device__ __forceinline__ void bfsplit(float x, u16& h, u16& l) {
    unsigned u = __float_as_uint(x);
    unsigned hb = (u + 0x7FFFu + ((u >> 16) & 1u)) >> 16;
    h = (u16)hb;
    float r = x - __uint_as_float(hb << 16);
    unsigned v = __float_as_uint(r);
    l = (u16)((v + 0x7FFFu + ((v >> 16) & 1u)) >> 16);
}

// exact *-2 on two packed bf16 (sign flip + exponent+1)
__device__ __forceinline__ unsigned nd2(unsigned v) {
    return (v ^ 0x80008000u) + 0x00800080u;
}

__device__ __forceinline__ bf16x8 pack8(unsigned a, unsigned b, unsigned c, unsigned d) {
    union { unsigned u[4]; bf16x8 v; } t;
    t.u[0] = a; t.u[1] = b; t.u[2] = c; t.u[3] = d;
    return t.v;
}

// Compact 16B/point: d0=xh|yh d1=zh|xl d2=yl|zl d3=s2h|s2l (bf16 splits).
// Logical K=16 (slots k16..31 = 0 via zeroed lanes 32..63):
//  row(g): k0..7={xh,yh,zh,xl,yl,zl,xh,yh}  k8..15={zh,xl,yl,zl,s2h,s2l,1,1}
//  col(p): a=-2p; k0..7={axh,ayh,azh,axh,ayh,azh,axl,ayl}
//          k8..15={azl,axl,ayl,azl,1,1,s2h,s2l}
//  dot = |g|^2 - 2 g.p + |p|^2 = d^2 (split products exact, fp32 accum).
__global__ __launch_bounds__(256) void chamfer_prep(
    const float* __restrict__ P, const float* __restrict__ G,
    uint4* __restrict__ Pc, uint4* __restrict__ Gc,
    unsigned* __restrict__ mins)
{
    const int i = blockIdx.x * 256 + (int)threadIdx.x;   // 0..65535
    mins[i] = 0x7F7F7F7Fu;                               // 3.39e38f sentinel
    const int set = i >> 15;
    const int idx = i & 32767;
    const float* src = set ? G : P;
    uint4* dst = set ? Gc : Pc;

    const float x = src[3*idx+0], y = src[3*idx+1], z = src[3*idx+2];
    const float s2 = fmaf(x, x, fmaf(y, y, z*z));
    u16 xh,xl,yh,yl,zh,zl,sh,sl;
    bfsplit(x,xh,xl); bfsplit(y,yh,yl); bfsplit(z,zh,zl); bfsplit(s2,sh,sl);

    uint4 q;
    q.x = (unsigned)xh | ((unsigned)yh << 16);
    q.y = (unsigned)zh | ((unsigned)xl << 16);
    q.z = (unsigned)yl | ((unsigned)zl << 16);
    q.w = (unsigned)sh | ((unsigned)sl << 16);
    dst[idx] = q;
}

__global__ __launch_bounds__(256, 4) void chamfer_mfma(
    const uint4* __restrict__ Pc, const uint4* __restrict__ Gc,
    unsigned* __restrict__ mins)
{
    const int l = (int)threadIdx.x & 63;
    int w = blockIdx.x * 4 + ((int)threadIdx.x >> 6);
    const int dir = (w >= WPD) ? 1 : 0;
    if (dir) w -= WPD;
    const uint4* rowC = dir ? Pc : Gc;       // dir0: rows=gt, cols=pred -> minP
    const uint4* colC = dir ? Gc : Pc;
    unsigned* outMin = mins + (dir ? BATCH*NPTS : 0);
    const int rc = w & (RCH-1);
    const int cg = (w >> 4) & (CG-1);
    const int b  = w >> 10;

    const bool lo32 = (l < 32), lo16 = (l < 16);
    const int lp = l & 15;
    const uint4 z4 = {0,0,0,0};
    const unsigned ONE2 = 0x3F803F80u;
    const f32x4 zacc = {0,0,0,0};

    // ================= self-probe: measure the C/D composite map =================
    // Probe 1 (col map): A == 1.0 everywhere, B(lane) == 2^(lane&15) in all elems.
    // C(l,reg) = sum_k 1 * 2^c = 32 * 2^c where c = col-point under MY placement.
    bf16x8 pa = pack8(ONE2, ONE2, ONE2, ONE2);
    const unsigned eb = (127u + (unsigned)lp) << 7;         // bf16 bits of 2^lp
    const unsigned eb2 = eb | (eb << 16);
    bf16x8 pb = pack8(eb2, eb2, eb2, eb2);
    f32x4 pcol = __builtin_amdgcn_mfma_f32_16x16x32_bf16(pa, pb, zacc, 0, 0, 0);
    int cmap0 = (int)((__float_as_uint(pcol[0]) >> 23) & 255u) - 132;
    int cmap1 = (int)((__float_as_uint(pcol[1]) >> 23) & 255u) - 132;
    int cmap2 = (int)((__float_as_uint(pcol[2]) >> 23) & 255u) - 132;
    int cmap3 = (int)((__float_as_uint(pcol[3]) >> 23) & 255u) - 132;
    const bool okA = (cmap0==lp) & (cmap1==lp) & (cmap2==lp) & (cmap3==lp);
    const bool flagA = (bool)__all((int)okA);
    // Path-B validity: cmap uniform within each 16-lane group
    bool okB = (cmap0 == __shfl(cmap0, l & 48)) & (cmap1 == __shfl(cmap1, l & 48))
             & (cmap2 == __shfl(cmap2, l & 48)) & (cmap3 == __shfl(cmap3, l & 48));
    const bool flagB = (bool)__all((int)okB);
    // Probe 2 (pairing): A == B == 2^e per element. If HW pairs A(g,e)<->B(g,e):
    // C = 4 * sum_e 4^e = 87380 exactly, everywhere.
    const unsigned g01 = (127u<<7) | ((128u<<7)<<16);
    const unsigned g23 = (129u<<7) | ((130u<<7)<<16);
    const unsigned g45 = (131u<<7) | ((132u<<7)<<16);
    const unsigned g67 = (133u<<7) | ((134u<<7)<<16);
    bf16x8 pe = pack8(g01, g23, g45, g67);
    f32x4 pp = __builtin_amdgcn_mfma_f32_16x16x32_bf16(pe, pe, zacc, 0, 0, 0);
    const bool okP = (pp[0]==87380.0f)&(pp[1]==87380.0f)&(pp[2]==87380.0f)&(pp[3]==87380.0f);
    const bool flagP = (bool)__all((int)okP);

    // ================= build 8 col fragments in-register =================
    bf16x8 cf[CTW];
    float rmin[CTW][4];
    const int cbase = b*NPTS + cg*(CTW*16) + lp;
#pragma unroll
    for (int i = 0; i < CTW; ++i) {
        const uint4 c = lo32 ? colC[cbase + i*16] : z4;
        const unsigned n0 = nd2(c.x), n1 = nd2(c.y), n2 = nd2(c.z);
        unsigned e0, e1, e2, e3;
        if (lo16) {
            e0 = n0;                                   // axh|ayh
            e1 = (n1 & 0xFFFFu) | (n0 << 16);          // azh|axh
            e2 = (n0 >> 16)     | (n1 << 16);          // ayh|azh
            e3 = (n1 >> 16)     | (n2 << 16);          // axl|ayl
        } else {
            e0 = (n2 >> 16) | (n1 & 0xFFFF0000u);      // azl|axl
            e1 = n2;                                   // ayl|azl
            e2 = ONE2;                                 // 1|1
            e3 = c.w;                                  // s2h|s2l
        }
        if (!lo32) { e0 = e1 = e2 = e3 = 0; }
        cf[i] = pack8(e0, e1, e2, e3);
        rmin[i][0] = rmin[i][1] = rmin[i][2] = rmin[i][3] = 3.0e38f;
    }

    // ================= walk 32 row tiles (per-reg mins: layout-agnostic) ========
    const int rbase = b*NPTS + rc*512 + lp;
    uint4 rcur = lo32 ? rowC[rbase] : z4;
#pragma unroll 1
    for (int t = 0; t < RTW; ++t) {
        const int tn = (t+1 < RTW) ? (t+1) : t;
        const uint4 rnxt = lo32 ? rowC[rbase + tn*16] : z4;
        unsigned r0, r1, r2, r3;
        if (lo16) { r0 = rcur.x; r1 = rcur.y; r2 = rcur.z; r3 = rcur.x; }
        else      { r0 = rcur.y; r1 = rcur.z; r2 = rcur.w; r3 = ONE2;   }
        if (!lo32) { r0 = r1 = r2 = r3 = 0; }
        const bf16x8 rf = pack8(r0, r1, r2, r3);
#pragma unroll
        for (int i = 0; i < CTW; ++i) {
            f32x4 acc = __builtin_amdgcn_mfma_f32_16x16x32_bf16(rf, cf[i], zacc, 0, 0, 0);
            rmin[i][0] = fminf(rmin[i][0], acc[0]);
            rmin[i][1] = fminf(rmin[i][1], acc[1]);
            rmin[i][2] = fminf(rmin[i][2], acc[2]);
            rmin[i][3] = fminf(rmin[i][3], acc[3]);
        }
        rcur = rnxt;
    }

    // ================= probe-selected epilogue =================
    const int obase = b*NPTS + cg*(CTW*16);
    if (flagP && flagA) {
        // col = lane&15; regs+groups are rows
#pragma unroll
        for (int i = 0; i < CTW; ++i) {
            float v = fminf(fminf(rmin[i][0], rmin[i][1]), fminf(rmin[i][2], rmin[i][3]));
            v = fminf(v, __shfl_xor(v, 16));
            v = fminf(v, __shfl_xor(v, 32));
            if (lo16) atomicMin(&outMin[obase + i*16 + l], __float_as_uint(fmaxf(v, 0.0f)));
        }
    } else if (flagP && flagB) {
        // col = cmap[reg] (per group); lanes within a group are rows
#pragma unroll
        for (int i = 0; i < CTW; ++i) {
#pragma unroll
            for (int r = 0; r < 4; ++r) {
                float v = rmin[i][r];
                v = fminf(v, __shfl_xor(v, 1));
                v = fminf(v, __shfl_xor(v, 2));
                v = fminf(v, __shfl_xor(v, 4));
                v = fminf(v, __shfl_xor(v, 8));
                const int cm = (r==0)?cmap0:(r==1)?cmap1:(r==2)?cmap2:cmap3;
                if (lp == 0) atomicMin(&outMin[obase + i*16 + cm], __float_as_uint(fmaxf(v, 0.0f)));
            }
        }
    } else {
        // diagnostic beacon: 777 -> pairing broken; 333 -> exotic C layout
        const float beacon = flagP ? 333.0f : 777.0f;
#pragma unroll
        for (int i = 0; i < CTW; ++i)
            if (lo16) outMin[obase + i*16 + l] = __float_as_uint(beacon);
    }
}

__global__ __launch_bounds__(1024) void chamfer_reduce_kernel(
    const uint4* __restrict__ mins4, float* __restrict__ out, int q4P, int q4G)
{
    __shared__ double sdata[1024];
    const double wP = 1.0 / (4.0 * (double)q4P);
    const double wG = 1.0 / (4.0 * (double)q4G);
    double acc = 0.0;
    const int tot = q4P + q4G;
    for (int i = (int)threadIdx.x; i < tot; i += 1024) {
        const uint4 v = mins4[i];
        const double s = (double)__uint_as_float(v.x) + (double)__uint_as_float(v.y)
                       + (double)__uint_as_float(v.z) + (double)__uint_as_float(v.w);
        acc += (i < q4P) ? s * wP : s * wG;
    }
    sdata[threadIdx.x] = acc;
    __syncthreads();
    for (int off = 512; off > 0; off >>= 1) {
        if ((int)threadIdx.x < off) sdata[threadIdx.x] += sdata[threadIdx.x + off];
        __syncthreads();
    }
    if (threadIdx.x == 0) out[0] = (float)sdata[0];
}

extern "C" void kernel_launch(void* const* d_in, const int* in_sizes, int n_in,
                              void* d_out, int out_size, void* d_ws, size_t ws_size,
                              hipStream_t stream) {
    const float* pred = (const float*)d_in[0];
    const float* gt   = (const float*)d_in[1];
    float* out = (float*)d_out;
    (void)in_sizes; (void)n_in; (void)out_size; (void)ws_size;

    // ws layout (1.25 MB, proven-safe footprint): [Pc 512KB][Gc 512KB][mins 256KB]
    uint4* Pc = (uint4*)d_ws;
    uint4* Gc = Pc + BATCH * NPTS;
    unsigned* mins = (unsigned*)(Gc + BATCH * NPTS);

    chamfer_prep<<<(BATCH * NPTS * 2) / 256, 256, 0, stream>>>(pred, gt, Pc, Gc, mins);

    chamfer_mfma<<<(WPD * 2) / 4, 256, 0, stream>>>(Pc, Gc, mins);

    chamfer_reduce_kernel<<<1, 1024, 0, stream>>>(
        (const uint4*)mins, out, BATCH * NPTS / 4, BATCH * NPTS / 4);
}

// Round 10
// 79.104 us; speedup vs baseline: 1.2185x; 1.2185x over previous
//
#include <hip/hip_runtime.h>

typedef float f32x4  __attribute__((ext_vector_type(4)));
typedef short bf16x8 __attribute__((ext_vector_type(8)));
typedef unsigned short u16;

#define BATCH 4
#define NPTS  8192
#define CTW   4                  // output tiles per wave -> 64 outputs
#define OG    (NPTS/(16*CTW))    // 128 output groups per batch
#define CC    4                  // candidate chunks per batch
#define CPC   (NPTS/CC)          // 2048 candidates per chunk (128 tiles)
#define WPD   (BATCH*OG*CC)      // 2048 waves per direction

// RNE bf16 split: x ~= h + l
__device__ __forceinline__ void bfsplit(float x, u16& h, u16& l) {
    unsigned u = __float_as_uint(x);
    unsigned hb = (u + 0x7FFFu + ((u >> 16) & 1u)) >> 16;
    h = (u16)hb;
    float r = x - __uint_as_float(hb << 16);
    unsigned v = __float_as_uint(r);
    l = (u16)((v + 0x7FFFu + ((v >> 16) & 1u)) >> 16);
}

// exact *-2 on two packed bf16 (sign flip + exponent+1)
__device__ __forceinline__ unsigned nd2(unsigned v) {
    return (v ^ 0x80008000u) + 0x00800080u;
}

__device__ __forceinline__ bf16x8 pack8(unsigned a, unsigned b, unsigned c, unsigned d) {
    union { unsigned u[4]; bf16x8 v; } t;
    t.u[0] = a; t.u[1] = b; t.u[2] = c; t.u[3] = d;
    return t.v;
}

// Compact 16B/point: q.x=xh|yh q.y=zh|xl q.z=yl|zl q.w=s2h|s2l (bf16 splits).
// 16x16x32 bf16. This kernel is the round-6 VERIFIED composite (absmax 0.0):
//   arg0 = candidates (min-over side), arg1 = outputs; shared assumed k-map;
//   D-layout handled by RUNTIME-measured cmap (out-pt = cmap(group,reg)) +
//   lanes-within-group fold (any lane bijection cancels under min).
//  arg0 g4=0: {gxh,gyh,gzh, gxl,gyl,gzl, gxh,gyh}  g4=1: {gzh, gxl,gyl,gzl, s2h,s2l, 1,1}
//  arg1 g4=0: {axh,ayh,azh, axh,ayh,azh, axl,ayl}  g4=1: {azl, axl,ayl,azl, 1,1, s2h,s2l}
//  (a=-2p)  dot = |g|^2 - 2 g.p + |p|^2 = d^2, fp32 accum, split products exact.
__global__ __launch_bounds__(256) void chamfer_prep(
    const float* __restrict__ P, const float* __restrict__ G,
    uint4* __restrict__ Pc, uint4* __restrict__ Gc,
    unsigned* __restrict__ mins)
{
    const int i = blockIdx.x * 256 + (int)threadIdx.x;   // 0..65535
    mins[i] = 0x7F7F7F7Fu;                               // 3.39e38f sentinel
    const int set = i >> 15;
    const int idx = i & 32767;
    const float* src = set ? G : P;
    uint4* dst = set ? Gc : Pc;

    const float x = src[3*idx+0], y = src[3*idx+1], z = src[3*idx+2];
    const float s2 = fmaf(x, x, fmaf(y, y, z*z));
    u16 xh,xl,yh,yl,zh,zl,sh,sl;
    bfsplit(x,xh,xl); bfsplit(y,yh,yl); bfsplit(z,zh,zl); bfsplit(s2,sh,sl);

    uint4 q;
    q.x = (unsigned)xh | ((unsigned)yh << 16);
    q.y = (unsigned)zh | ((unsigned)xl << 16);
    q.z = (unsigned)yl | ((unsigned)zl << 16);
    q.w = (unsigned)sh | ((unsigned)sl << 16);
    dst[idx] = q;
}

__global__ __launch_bounds__(256) void chamfer_mfma(
    const uint4* __restrict__ Pc, const uint4* __restrict__ Gc,
    unsigned* __restrict__ mins)
{
    const int l = (int)threadIdx.x & 63;
    int w = blockIdx.x * 4 + ((int)threadIdx.x >> 6);
    const int dir = (w >= WPD) ? 1 : 0;
    if (dir) w -= WPD;
    const uint4* cndC = dir ? Pc : Gc;   // arg0: candidates (dir0: gt)
    const uint4* outC = dir ? Gc : Pc;   // arg1: outputs    (dir0: pred)
    unsigned* outMin = mins + (dir ? BATCH*NPTS : 0);
    // w bits: [b:2][og_hi:5][cc:2][og_lo:2] -> block's 4 waves share cc (L1 reuse)
    const int og = (((w >> 4) & 31) << 2) | (w & 3);
    const int cc = (w >> 2) & (CC-1);
    const int b  = w >> 9;

    const int lp = l & 15;
    const int g4 = l >> 4;               // k-groups; 2,3 carry zeros
    const unsigned ONE2 = 0x3F803F80u;
    const f32x4 zacc = {0,0,0,0};
    const uint4 z4 = {0,0,0,0};

    // ===== runtime probe (round-6 verbatim): measure out-pt map cmap(g,r) =====
    // P1: arg0 == 1.0 all, arg1(lane) == 2^(lane&15) all elems.
    // D(l,r) = 32 * 2^(out-pt) -> cmap from exponent.
    {
    }
    const bf16x8 pa1 = pack8(ONE2, ONE2, ONE2, ONE2);
    const unsigned eb = (127u + (unsigned)lp) << 7;
    const unsigned eb2 = eb | (eb << 16);
    const bf16x8 pb1 = pack8(eb2, eb2, eb2, eb2);
    const f32x4 pcol = __builtin_amdgcn_mfma_f32_16x16x32_bf16(pa1, pb1, zacc, 0, 0, 0);
    const int cmap0 = (int)((__float_as_uint(pcol[0]) >> 23) & 255u) - 132;
    const int cmap1 = (int)((__float_as_uint(pcol[1]) >> 23) & 255u) - 132;
    const int cmap2 = (int)((__float_as_uint(pcol[2]) >> 23) & 255u) - 132;
    const int cmap3 = (int)((__float_as_uint(pcol[3]) >> 23) & 255u) - 132;
    const bool okA = (cmap0==lp) & (cmap1==lp) & (cmap2==lp) & (cmap3==lp);
    const bool flagA = (bool)__all((int)okA);
    bool okB = (cmap0 == __shfl(cmap0, l & 48)) & (cmap1 == __shfl(cmap1, l & 48))
             & (cmap2 == __shfl(cmap2, l & 48)) & (cmap3 == __shfl(cmap3, l & 48));
    const bool flagB = (bool)__all((int)okB);
    // P2: A=B, elem e = 2^e on every lane -> 4 * sum_e 4^e = 87380 exactly.
    const unsigned h01 = (127u<<7) | ((128u<<7)<<16);
    const unsigned h23 = (129u<<7) | ((130u<<7)<<16);
    const unsigned h45 = (131u<<7) | ((132u<<7)<<16);
    const unsigned h67 = (133u<<7) | ((134u<<7)<<16);
    const bf16x8 pe = pack8(h01, h23, h45, h67);
    const f32x4 p2 = __builtin_amdgcn_mfma_f32_16x16x32_bf16(pe, pe, zacc, 0, 0, 0);
    bool okP = true;
#pragma unroll
    for (int r = 0; r < 4; ++r) okP &= (p2[r] == 87380.0f);
    const bool flagP = (bool)__all((int)okP);
    // pack cmap into one reg (4x4 bits) to carry across the loop
    const unsigned cpack = (unsigned)cmap0 | ((unsigned)cmap1 << 4)
                         | ((unsigned)cmap2 << 8) | ((unsigned)cmap3 << 12);

    // ===== output frags on arg1, built once per wave =====
    bf16x8 cf[CTW];
    float rmin[CTW][4];
    const int cbase = b*NPTS + og*(CTW*16) + lp;
#pragma unroll
    for (int i = 0; i < CTW; ++i) {
        const uint4 c = (g4 < 2) ? outC[cbase + i*16] : z4;
        const unsigned n0 = nd2(c.x), n1 = nd2(c.y), n2 = nd2(c.z);
        unsigned e0, e1, e2, e3;
        if (g4 == 0) {
            e0 = n0;                                   // axh|ayh
            e1 = (n1 & 0xFFFFu) | (n0 << 16);          // azh|axh
            e2 = (n0 >> 16)     | (n1 << 16);          // ayh|azh
            e3 = (n1 >> 16)     | (n2 << 16);          // axl|ayl
        } else if (g4 == 1) {
            e0 = (n2 >> 16) | (n1 & 0xFFFF0000u);      // azl|axl
            e1 = n2;                                   // ayl|azl
            e2 = ONE2;                                 // 1|1
            e3 = c.w;                                  // s2h|s2l
        } else { e0 = e1 = e2 = e3 = 0; }
        cf[i] = pack8(e0, e1, e2, e3);
        rmin[i][0] = rmin[i][1] = rmin[i][2] = rmin[i][3] = 3.0e38f;
    }

    // ===== stream candidates: 2 tiles per step, per-reg mins (layout-agnostic) ====
    const int rbase = b*NPTS + cc*CPC + lp;
#pragma unroll 1
    for (int t = 0; t < CPC/16; t += 2) {
        const uint4 qa = (g4 < 2) ? cndC[rbase + t*16]      : z4;
        const uint4 qb = (g4 < 2) ? cndC[rbase + t*16 + 16] : z4;
        unsigned a0,a1,a2,a3, b0,b1,b2,b3;
        if (g4 == 0)      { a0=qa.x; a1=qa.y; a2=qa.z; a3=qa.x;  b0=qb.x; b1=qb.y; b2=qb.z; b3=qb.x; }
        else if (g4 == 1) { a0=qa.y; a1=qa.z; a2=qa.w; a3=ONE2;  b0=qb.y; b1=qb.z; b2=qb.w; b3=ONE2; }
        else              { a0=a1=a2=a3=0;               b0=b1=b2=b3=0; }
        const bf16x8 rfa = pack8(a0, a1, a2, a3);
        const bf16x8 rfb = pack8(b0, b1, b2, b3);
#pragma unroll
        for (int i = 0; i < CTW; ++i) {
            const f32x4 da = __builtin_amdgcn_mfma_f32_16x16x32_bf16(rfa, cf[i], zacc, 0, 0, 0);
            const f32x4 db = __builtin_amdgcn_mfma_f32_16x16x32_bf16(rfb, cf[i], zacc, 0, 0, 0);
            rmin[i][0] = fminf(fminf(da[0], db[0]), rmin[i][0]);   // -> v_min3
            rmin[i][1] = fminf(fminf(da[1], db[1]), rmin[i][1]);
            rmin[i][2] = fminf(fminf(da[2], db[2]), rmin[i][2]);
            rmin[i][3] = fminf(fminf(da[3], db[3]), rmin[i][3]);
        }
    }

    // ===== epilogue: probe-selected (round-6 verified = path B) =====
    const int obase = b*NPTS + og*(CTW*16);
    if (flagP && flagB && !flagA) {
        // out-pt = cmap(g,r); lanes within group are candidates -> fold xor1/2/4/8
#pragma unroll
        for (int i = 0; i < CTW; ++i) {
#pragma unroll
            for (int r = 0; r < 4; ++r) {
                float v = rmin[i][r];
                v = fminf(v, __shfl_xor(v, 1));
                v = fminf(v, __shfl_xor(v, 2));
                v = fminf(v, __shfl_xor(v, 4));
                v = fminf(v, __shfl_xor(v, 8));
                const int cm = (int)((cpack >> (4*r)) & 15u);
                if (lp == 0)
                    atomicMin(&outMin[obase + i*16 + cm], __float_as_uint(fmaxf(v, 0.0f)));
            }
        }
    } else if (flagP && flagA) {
        // out-pt = lane&15; regs+groups are candidates
#pragma unroll
        for (int i = 0; i < CTW; ++i) {
            float v = fminf(fminf(rmin[i][0], rmin[i][1]), fminf(rmin[i][2], rmin[i][3]));
            v = fminf(v, __shfl_xor(v, 16));
            v = fminf(v, __shfl_xor(v, 32));
            if (l < 16)
                atomicMin(&outMin[obase + i*16 + l], __float_as_uint(fmaxf(v, 0.0f)));
        }
    } else {
        const float beacon = flagP ? 333.0f : 777.0f;   // 333: cmap shape, 777: pairing
        if (l < 16)
#pragma unroll
            for (int i = 0; i < CTW; ++i)
                outMin[obase + i*16 + l] = __float_as_uint(beacon);
    }
}

__global__ __launch_bounds__(1024) void chamfer_reduce_kernel(
    const uint4* __restrict__ mins4, float* __restrict__ out, int q4P, int q4G)
{
    __shared__ double sdata[1024];
    const double wP = 1.0 / (4.0 * (double)q4P);
    const double wG = 1.0 / (4.0 * (double)q4G);
    double acc = 0.0;
    const int tot = q4P + q4G;
    for (int i = (int)threadIdx.x; i < tot; i += 1024) {
        const uint4 v = mins4[i];
        const double s = (double)__uint_as_float(v.x) + (double)__uint_as_float(v.y)
                       + (double)__uint_as_float(v.z) + (double)__uint_as_float(v.w);
        acc += (i < q4P) ? s * wP : s * wG;
    }
    sdata[threadIdx.x] = acc;
    __syncthreads();
    for (int off = 512; off > 0; off >>= 1) {
        if ((int)threadIdx.x < off) sdata[threadIdx.x] += sdata[threadIdx.x + off];
        __syncthreads();
    }
    if (threadIdx.x == 0) out[0] = (float)sdata[0];
}

extern "C" void kernel_launch(void* const* d_in, const int* in_sizes, int n_in,
                              void* d_out, int out_size, void* d_ws, size_t ws_size,
                              hipStream_t stream) {
    const float* pred = (const float*)d_in[0];
    const float* gt   = (const float*)d_in[1];
    float* out = (float*)d_out;
    (void)in_sizes; (void)n_in; (void)out_size; (void)ws_size;

    // ws layout (1.25 MB, proven-safe): [Pc 512KB][Gc 512KB][mins 256KB]
    uint4* Pc = (uint4*)d_ws;
    uint4* Gc = Pc + BATCH * NPTS;
    unsigned* mins = (unsigned*)(Gc + BATCH * NPTS);

    chamfer_prep<<<(BATCH * NPTS * 2) / 256, 256, 0, stream>>>(pred, gt, Pc, Gc, mins);

    chamfer_mfma<<<(WPD * 2) / 4, 256, 0, stream>>>(Pc, Gc, mins);

    chamfer_reduce_kernel<<<1, 1024, 0, stream>>>(
        (const uint4*)mins, out, BATCH * NPTS / 4, BATCH * NPTS / 4);
}